// Round 9
// baseline (3466.684 us; speedup 1.0000x reference)
//
#include <hip/hip_runtime.h>

#define SEQ  512
#define IDIM 256
#define HD   1024
#define BT   256
#define NCLS 10

#define GR   8         // row groups (128 rows each)
#define GB   16        // batch groups (16 cols each)
#define NWG  (GR*GB)   // 128 WGs
#define TPB  512       // 8 waves
#define KKH  32        // h kk-blocks (K=1024)
#define KKX  8         // x kk-blocks (K=256)

typedef __attribute__((ext_vector_type(8))) short short8;
typedef __attribute__((ext_vector_type(4))) float f32x4;
typedef __attribute__((ext_vector_type(4))) unsigned short us4;
typedef __attribute__((ext_vector_type(4))) int i32x4;

// h double buffer, B-fragment order per col-group (R7 layout).
// All cross-WG traffic via system-scope (sc0+sc1) ops at the LLC --
// placement-independent, R5/R7-proven protocol. No placement fast path.
__device__ unsigned short g_h[2][GB][KKH*64*8];
__device__ float g_hfinal[BT][HD];
__device__ int g_flag[GB][16];            // 8 used, one line per group
__device__ unsigned int g_done[GB*16];    // padded done counters

__device__ __forceinline__ unsigned short f2bf(float f){
    unsigned int u = __builtin_bit_cast(unsigned int, f);
    u += 0x7fffu + ((u >> 16) & 1u);      // round-to-nearest-even
    return (unsigned short)(u >> 16);
}
__device__ __forceinline__ float fast_tanh(float v){
    float e = __expf(2.0f * v);           // exact: tanh = 1 - 2/(e^2v+1)
    return 1.0f - 2.0f / (e + 1.0f);
}
__device__ __forceinline__ void sys_st64(unsigned short* p, unsigned long long v){
    __hip_atomic_store((unsigned long long*)p, v, __ATOMIC_RELAXED, __HIP_MEMORY_SCOPE_SYSTEM);
}
__device__ __forceinline__ void sys_st32(int* p, int v){
    __hip_atomic_store(p, v, __ATOMIC_RELAXED, __HIP_MEMORY_SCOPE_SYSTEM);
}
__device__ __forceinline__ int sys_ld32(const int* p){
    return __hip_atomic_load(p, __ATOMIC_RELAXED, __HIP_MEMORY_SCOPE_SYSTEM);
}

__global__ __launch_bounds__(TPB, 1)
__attribute__((amdgpu_waves_per_eu(2, 2)))
void rnn_main(
    const float* __restrict__ x, const float* __restrict__ w_hx,
    const float* __restrict__ w_hh, const float* __restrict__ b_h)
{
    __shared__ unsigned short sB[KKH*64*8];     // 32 KB staged h slab
    __shared__ unsigned short sX[8*KKX*64*8];   // 64 KB W_hx A-frags (per wave)

    const int tid = threadIdx.x;
    const int wg  = blockIdx.x;
    const int gbg = wg & (GB-1);
    const int gr  = wg >> 4;
    const int r0  = gr * 128;
    const int b0  = gbg * 16;
    const int l   = tid & 63;
    const int w   = tid >> 6;
    const int rw  = r0 + w*16;
    const int row = rw + (l & 15);
    const int ko  = (l >> 4) << 3;

    // ---- W_hh -> registers (128 VGPRs; A-frag bijection proven R1-R8)
    short8 wa[KKH];
    #pragma unroll
    for (int kk = 0; kk < KKH; ++kk){
        f32x4 v0 = *(const f32x4*)(w_hh + (size_t)row*HD + kk*32 + ko);
        f32x4 v1 = *(const f32x4*)(w_hh + (size_t)row*HD + kk*32 + ko + 4);
        short8 a;
        a[0]=(short)f2bf(v0[0]); a[1]=(short)f2bf(v0[1]);
        a[2]=(short)f2bf(v0[2]); a[3]=(short)f2bf(v0[3]);
        a[4]=(short)f2bf(v1[0]); a[5]=(short)f2bf(v1[1]);
        a[6]=(short)f2bf(v1[2]); a[7]=(short)f2bf(v1[3]);
        wa[kk] = a;
    }
    // ---- W_hx A-frags -> LDS (keeps register count bounded)
    #pragma unroll
    for (int xk = 0; xk < KKX; ++xk){
        f32x4 v0 = *(const f32x4*)(w_hx + (size_t)row*IDIM + xk*32 + ko);
        f32x4 v1 = *(const f32x4*)(w_hx + (size_t)row*IDIM + xk*32 + ko + 4);
        short8 a;
        a[0]=(short)f2bf(v0[0]); a[1]=(short)f2bf(v0[1]);
        a[2]=(short)f2bf(v0[2]); a[3]=(short)f2bf(v0[3]);
        a[4]=(short)f2bf(v1[0]); a[5]=(short)f2bf(v1[1]);
        a[6]=(short)f2bf(v1[2]); a[7]=(short)f2bf(v1[3]);
        *(short8*)&sX[(size_t)((w*KKX + xk)*64 + l)*8] = a;
    }

    const f32x4 bias = *(const f32x4*)(b_h + rw + ((l >> 4) << 2));
    const float* xlane = x + (size_t)(b0 + (l & 15))*(SEQ*IDIM) + ko;

    // ---- zero our kk-range of buf0 in global (for the 7 foreign readers)
    {
        int kkz = gr*4 + (tid >> 7);
        int rem = tid & 127;
        sys_st64(&g_h[0][gbg][(size_t)kkz*512 + rem*4], 0ull);
    }

    // constant self-stage / store offset (B-frag position of this thread's h)
    const int rloc  = w*16 + ((l >> 4) << 2);
    const int kkd   = gr*4 + (rloc >> 5);
    const int lnp   = (l & 15) | (((rloc >> 3) & 3) << 4);
    const int sboff = kkd*512 + lnp*8 + (rloc & 7);
    us4 hw_prev = {0, 0, 0, 0};               // h_0 = 0 for self-staging

    asm volatile("s_waitcnt vmcnt(0)" ::: "memory");
    __syncthreads();
    if (tid == 0) sys_st32(&g_flag[gbg][gr], 1);   // buf0 zeros published

    // ---- x-part prologue for t=0
    f32x4 accX = bias;
    #pragma unroll
    for (int xk = 0; xk < KKX; ++xk){
        f32x4 v0 = *(const f32x4*)(xlane + xk*32);
        f32x4 v1 = *(const f32x4*)(xlane + xk*32 + 4);
        short8 bx;
        bx[0]=(short)f2bf(v0[0]); bx[1]=(short)f2bf(v0[1]);
        bx[2]=(short)f2bf(v0[2]); bx[3]=(short)f2bf(v0[3]);
        bx[4]=(short)f2bf(v1[0]); bx[5]=(short)f2bf(v1[1]);
        bx[6]=(short)f2bf(v1[2]); bx[7]=(short)f2bf(v1[3]);
        short8 a = *(const short8*)&sX[(size_t)((w*KKX + xk)*64 + l)*8];
        accX = __builtin_amdgcn_mfma_f32_16x16x32_bf16(a, bx, accX, 0, 0, 0);
    }

    const int* fl = &g_flag[gbg][0];

    for (int t = 0; t < SEQ; ++t){
        const int rb = t & 1;
        f32x4 acc = accX;
        const unsigned short* slab = &g_h[rb][gbg][0];

        // ---- wait chunk A (producers 0..3)
        if (w == 0){
            const int val = t + 1;
            const int* pp = fl + (l & 3);
            int guard = 0;
            for (;;){
                int f = sys_ld32(pp);
                if (__all(f >= val)) break;
                if (++guard > (1 << 20)) break;   // hang safety
            }
        }
        __syncthreads();

        // ---- stage: self blocks (from registers) + chunk-A foreign blocks
        *(us4*)&sB[sboff] = hw_prev;              // 4 KB collectively = own 4 blocks
        if ((w >> 1) != gr){                      // wave's A-blocks are foreign
            const int blk = w*2;                  // blocks blk, blk+1 (0..15)
            i32x4 va, vb;
            const unsigned short* pa = slab + (size_t)blk*512 + l*8;
            asm volatile("global_load_dwordx4 %0, %1, off sc0 sc1" : "=v"(va) : "v"(pa));
            asm volatile("global_load_dwordx4 %0, %1, off sc0 sc1" : "=v"(vb) : "v"(pa + 512));
            asm volatile("s_waitcnt vmcnt(0)" ::: "memory");
            *(i32x4*)&sB[(size_t)blk*512 + l*8]       = va;
            *(i32x4*)&sB[(size_t)(blk+1)*512 + l*8]   = vb;
        }
        __syncthreads();

        // ---- MFMA chunk A: kk 0..15
        #pragma unroll
        for (int kk = 0; kk < 16; ++kk){
            short8 b = *(const short8*)&sB[(size_t)(kk*64 + l)*8];
            acc = __builtin_amdgcn_mfma_f32_16x16x32_bf16(wa[kk], b, acc, 0, 0, 0);
        }

        // ---- wait chunk B (producers 4..7) -- usually already landed
        if (w == 0){
            const int val = t + 1;
            const int* pp = fl + 4 + (l & 3);
            int guard = 0;
            for (;;){
                int f = sys_ld32(pp);
                if (__all(f >= val)) break;
                if (++guard > (1 << 20)) break;
            }
        }
        __syncthreads();

        // ---- stage chunk-B foreign blocks (16..31)
        if ((4 + (w >> 1)) != gr){
            const int blk = 16 + w*2;
            i32x4 va, vb;
            const unsigned short* pa = slab + (size_t)blk*512 + l*8;
            asm volatile("global_load_dwordx4 %0, %1, off sc0 sc1" : "=v"(va) : "v"(pa));
            asm volatile("global_load_dwordx4 %0, %1, off sc0 sc1" : "=v"(vb) : "v"(pa + 512));
            asm volatile("s_waitcnt vmcnt(0)" ::: "memory");
            *(i32x4*)&sB[(size_t)blk*512 + l*8]       = va;
            *(i32x4*)&sB[(size_t)(blk+1)*512 + l*8]   = vb;
        }
        __syncthreads();

        // ---- MFMA chunk B: kk 16..31
        #pragma unroll
        for (int kk = 16; kk < KKH; ++kk){
            short8 b = *(const short8*)&sB[(size_t)(kk*64 + l)*8];
            acc = __builtin_amdgcn_mfma_f32_16x16x32_bf16(wa[kk], b, acc, 0, 0, 0);
        }

        float h0 = fast_tanh(acc[0]);
        float h1 = fast_tanh(acc[1]);
        float h2 = fast_tanh(acc[2]);
        float h3 = fast_tanh(acc[3]);

        if (t < SEQ-1){
            us4 hw = { f2bf(h0), f2bf(h1), f2bf(h2), f2bf(h3) };
            sys_st64(&g_h[rb ^ 1][gbg][sboff],
                     __builtin_bit_cast(unsigned long long, hw));
            hw_prev = hw;

            // ---- x-part for t+1 overlaps the store's LLC ack
            accX = bias;
            const float* xp = xlane + (size_t)(t+1)*IDIM;
            #pragma unroll
            for (int xk = 0; xk < KKX; ++xk){
                f32x4 v0 = *(const f32x4*)(xp + xk*32);
                f32x4 v1 = *(const f32x4*)(xp + xk*32 + 4);
                short8 bx;
                bx[0]=(short)f2bf(v0[0]); bx[1]=(short)f2bf(v0[1]);
                bx[2]=(short)f2bf(v0[2]); bx[3]=(short)f2bf(v0[3]);
                bx[4]=(short)f2bf(v1[0]); bx[5]=(short)f2bf(v1[1]);
                bx[6]=(short)f2bf(v1[2]); bx[7]=(short)f2bf(v1[3]);
                short8 a = *(const short8*)&sX[(size_t)((w*KKX + xk)*64 + l)*8];
                accX = __builtin_amdgcn_mfma_f32_16x16x32_bf16(a, bx, accX, 0, 0, 0);
            }

            asm volatile("s_waitcnt vmcnt(0)" ::: "memory");
            __syncthreads();                       // all 8 waves' h ack'd at LLC
            if (tid == 0) sys_st32(&g_flag[gbg][gr], t + 2);
        } else {
            f32x4 hf = {h0, h1, h2, h3};
            *(f32x4*)&g_hfinal[b0 + (l & 15)][r0 + rloc] = hf;
        }
    }

    // ---- epilogue: race-free flag reset for graph replay
    __syncthreads();
    if (tid == 0){
        __hip_atomic_fetch_add(&g_done[gbg*16], 1u, __ATOMIC_ACQ_REL, __HIP_MEMORY_SCOPE_SYSTEM);
        if (gr == 0){
            int guard = 0;
            while (__hip_atomic_load(&g_done[gbg*16], __ATOMIC_ACQUIRE, __HIP_MEMORY_SCOPE_SYSTEM) < GR
                   && ++guard < (1 << 22)) { }
            for (int i = 0; i < GR; ++i)
                sys_st32(&g_flag[gbg][i], 0);
            __hip_atomic_store(&g_done[gbg*16], 0u, __ATOMIC_RELAXED, __HIP_MEMORY_SCOPE_SYSTEM);
        }
    }
}

// p = w_ph @ h_final + b_p ; out[b][c]
__global__ __launch_bounds__(256, 1) void proj_kernel(
    const float* __restrict__ w_ph, const float* __restrict__ b_p, float* __restrict__ out)
{
    const int b   = blockIdx.x;
    const int tid = threadIdx.x;
    const int l   = tid & 63;
    const int wv  = tid >> 6;
    __shared__ float red[4];
    f32x4 hv = *(const f32x4*)(&g_hfinal[b][0] + tid*4);
    for (int c = 0; c < NCLS; ++c){
        f32x4 wvv = *(const f32x4*)(w_ph + c*HD + tid*4);
        float s = hv[0]*wvv[0] + hv[1]*wvv[1] + hv[2]*wvv[2] + hv[3]*wvv[3];
        #pragma unroll
        for (int off = 32; off; off >>= 1) s += __shfl_down(s, off, 64);
        if (l == 0) red[wv] = s;
        __syncthreads();
        if (tid == 0) out[b*NCLS + c] = red[0] + red[1] + red[2] + red[3] + b_p[c];
        __syncthreads();
    }
}

extern "C" void kernel_launch(void* const* d_in, const int* in_sizes, int n_in,
                              void* d_out, int out_size, void* d_ws, size_t ws_size,
                              hipStream_t stream) {
    const float* x    = (const float*)d_in[0];
    const float* w_hx = (const float*)d_in[1];
    const float* w_hh = (const float*)d_in[2];
    const float* b_h  = (const float*)d_in[3];
    const float* w_ph = (const float*)d_in[4];
    const float* b_p  = (const float*)d_in[5];

    void* args[] = { (void*)&x, (void*)&w_hx, (void*)&w_hh, (void*)&b_h };
    hipError_t err = hipLaunchCooperativeKernel((void*)rnn_main, dim3(NWG), dim3(TPB),
                                                args, 0, stream);
    if (err != hipSuccess) {
        rnn_main<<<dim3(NWG), dim3(TPB), 0, stream>>>(x, w_hx, w_hh, b_h);
    }
    proj_kernel<<<dim3(BT), dim3(256), 0, stream>>>(w_ph, b_p, (float*)d_out);
}

// Round 10
// 2986.699 us; speedup vs baseline: 1.1607x; 1.1607x over previous
//
#include <hip/hip_runtime.h>

#define SEQ  512
#define IDIM 256
#define HD   1024
#define BT   256
#define NCLS 10

#define GR   8         // row groups (128 rows each)
#define GB   16        // batch groups (16 cols each)
#define NWG  (GR*GB)   // 128 WGs
#define TPB  512       // 8 waves
#define KKH  32        // h kk-blocks (K=1024)
#define KKX  8         // x kk-blocks (K=256)

typedef __attribute__((ext_vector_type(8))) short short8;
typedef __attribute__((ext_vector_type(4))) float f32x4;
typedef __attribute__((ext_vector_type(4))) unsigned short us4;
typedef __attribute__((ext_vector_type(4))) int i32x4;

// h double buffer, B-fragment order per col-group (R7 layout).
// All cross-WG traffic via system-scope (sc0+sc1) ops at the LLC --
// placement-independent, R5/R7-proven protocol.
__device__ unsigned short g_h[2][GB][KKH*64*8];
__device__ float g_hfinal[BT][HD];
__device__ int g_flag[GB][16];            // 8 used, one 64B line per group
__device__ unsigned int g_done[GB*16];    // padded done counters

__device__ __forceinline__ unsigned short f2bf(float f){
    unsigned int u = __builtin_bit_cast(unsigned int, f);
    u += 0x7fffu + ((u >> 16) & 1u);      // round-to-nearest-even
    return (unsigned short)(u >> 16);
}
__device__ __forceinline__ float fast_tanh(float v){
    float e = __expf(2.0f * v);           // exact: tanh = 1 - 2/(e^2v+1)
    return 1.0f - 2.0f / (e + 1.0f);
}
__device__ __forceinline__ void sys_st64(unsigned short* p, unsigned long long v){
    __hip_atomic_store((unsigned long long*)p, v, __ATOMIC_RELAXED, __HIP_MEMORY_SCOPE_SYSTEM);
}
__device__ __forceinline__ void sys_st32(int* p, int v){
    __hip_atomic_store(p, v, __ATOMIC_RELAXED, __HIP_MEMORY_SCOPE_SYSTEM);
}
__device__ __forceinline__ int sys_ld32(const int* p){
    return __hip_atomic_load(p, __ATOMIC_RELAXED, __HIP_MEMORY_SCOPE_SYSTEM);
}

__global__
__attribute__((amdgpu_flat_work_group_size(TPB, TPB), amdgpu_waves_per_eu(2, 2)))
void rnn_main(
    const float* __restrict__ x, const float* __restrict__ w_hx,
    const float* __restrict__ w_hh, const float* __restrict__ b_h)
{
    __shared__ unsigned short sB[KKH*64*8];     // 32 KB staged h slab
    __shared__ unsigned short sX[8*KKX*64*8];   // 64 KB W_hx A-frags

    const int tid = threadIdx.x;
    const int wg  = blockIdx.x;
    const int gbg = wg & (GB-1);
    const int gr  = wg >> 4;
    const int r0  = gr * 128;
    const int b0  = gbg * 16;
    const int l   = tid & 63;
    const int w   = tid >> 6;
    const int rw  = r0 + w*16;
    const int row = rw + (l & 15);
    const int ko  = (l >> 4) << 3;

    // ---- W_hh -> registers, PINNED so the compiler cannot rematerialize.
    i32x4 wa[KKH];
    #pragma unroll
    for (int kk = 0; kk < KKH; ++kk){
        f32x4 v0 = *(const f32x4*)(w_hh + (size_t)row*HD + kk*32 + ko);
        f32x4 v1 = *(const f32x4*)(w_hh + (size_t)row*HD + kk*32 + ko + 4);
        us4 lo = { f2bf(v0[0]), f2bf(v0[1]), f2bf(v0[2]), f2bf(v0[3]) };
        us4 hi = { f2bf(v1[0]), f2bf(v1[1]), f2bf(v1[2]), f2bf(v1[3]) };
        unsigned long long a = __builtin_bit_cast(unsigned long long, lo);
        unsigned long long b = __builtin_bit_cast(unsigned long long, hi);
        i32x4 q;
        q[0] = (int)(a & 0xffffffffu); q[1] = (int)(a >> 32);
        q[2] = (int)(b & 0xffffffffu); q[3] = (int)(b >> 32);
        wa[kk] = q;
    }
    #pragma unroll
    for (int kk = 0; kk < KKH; ++kk)
        asm volatile("" : "+v"(wa[kk]));      // opaque: must stay in VGPRs

    // ---- W_hx A-frags -> LDS (bounds register count)
    #pragma unroll
    for (int xk = 0; xk < KKX; ++xk){
        f32x4 v0 = *(const f32x4*)(w_hx + (size_t)row*IDIM + xk*32 + ko);
        f32x4 v1 = *(const f32x4*)(w_hx + (size_t)row*IDIM + xk*32 + ko + 4);
        short8 a;
        a[0]=(short)f2bf(v0[0]); a[1]=(short)f2bf(v0[1]);
        a[2]=(short)f2bf(v0[2]); a[3]=(short)f2bf(v0[3]);
        a[4]=(short)f2bf(v1[0]); a[5]=(short)f2bf(v1[1]);
        a[6]=(short)f2bf(v1[2]); a[7]=(short)f2bf(v1[3]);
        *(short8*)&sX[(size_t)((w*KKX + xk)*64 + l)*8] = a;
    }

    const f32x4 bias = *(const f32x4*)(b_h + rw + ((l >> 4) << 2));
    const float* xlane = x + (size_t)(b0 + (l & 15))*(SEQ*IDIM) + ko;

    // ---- zero our kk-range of buf0 in global (for the 7 foreign readers)
    {
        int kkz = gr*4 + (tid >> 7);
        int rem = tid & 127;
        sys_st64(&g_h[0][gbg][(size_t)kkz*512 + rem*4], 0ull);
    }

    // constant self-stage / store offset (B-frag position of this thread's h)
    const int rloc  = w*16 + ((l >> 4) << 2);
    const int kkd   = gr*4 + (rloc >> 5);
    const int lnp   = (l & 15) | (((rloc >> 3) & 3) << 4);
    const int sboff = kkd*512 + lnp*8 + (rloc & 7);
    us4 hw_prev = {0, 0, 0, 0};               // h_0 = 0 for self-staging

    asm volatile("s_waitcnt vmcnt(0)" ::: "memory");
    __syncthreads();                          // zeros drained + sX staged
    if (tid == 0) sys_st32(&g_flag[gbg][gr], 1);

    // ---- x-part prologue for t=0
    f32x4 accX = bias;
    #pragma unroll
    for (int xk = 0; xk < KKX; ++xk){
        f32x4 v0 = *(const f32x4*)(xlane + xk*32);
        f32x4 v1 = *(const f32x4*)(xlane + xk*32 + 4);
        short8 bx;
        bx[0]=(short)f2bf(v0[0]); bx[1]=(short)f2bf(v0[1]);
        bx[2]=(short)f2bf(v0[2]); bx[3]=(short)f2bf(v0[3]);
        bx[4]=(short)f2bf(v1[0]); bx[5]=(short)f2bf(v1[1]);
        bx[6]=(short)f2bf(v1[2]); bx[7]=(short)f2bf(v1[3]);
        short8 a = *(const short8*)&sX[(size_t)((w*KKX + xk)*64 + l)*8];
        accX = __builtin_amdgcn_mfma_f32_16x16x32_bf16(a, bx, accX, 0, 0, 0);
    }

    const int* fl = &g_flag[gbg][0];

    for (int t = 0; t < SEQ; ++t){
        const int rb = t & 1;
        f32x4 acc = accX;
        const unsigned short* slab = &g_h[rb][gbg][0];

        // ---- wait: wave 0 polls all 8 producer flags (one 64B line)
        if (w == 0){
            const int val = t + 1;
            const int* pp = fl + (l & 7);
            int guard = 0;
            for (;;){
                int f = sys_ld32(pp);
                if (__all(f >= val)) break;
                if (++guard > (1 << 20)) break;   // hang safety
            }
        }
        __syncthreads();

        // ---- stage h slab: self blocks from registers, foreign from LLC.
        // wave w covers producer w's 4 kk-blocks (8 KB) unless w == gr.
        *(us4*)&sB[sboff] = hw_prev;              // own 4 blocks, collectively
        if (w != gr){
            const int blk = w*4;
            i32x4 v0, v1, v2, v3;
            const unsigned short* pa = slab + (size_t)blk*512 + l*8;
            asm volatile("global_load_dwordx4 %0, %1, off sc0 sc1" : "=v"(v0) : "v"(pa));
            asm volatile("global_load_dwordx4 %0, %1, off sc0 sc1" : "=v"(v1) : "v"(pa + 512));
            asm volatile("global_load_dwordx4 %0, %1, off sc0 sc1" : "=v"(v2) : "v"(pa + 1024));
            asm volatile("global_load_dwordx4 %0, %1, off sc0 sc1" : "=v"(v3) : "v"(pa + 1536));
            asm volatile("s_waitcnt vmcnt(0)" ::: "memory");
            *(i32x4*)&sB[(size_t)(blk+0)*512 + l*8] = v0;
            *(i32x4*)&sB[(size_t)(blk+1)*512 + l*8] = v1;
            *(i32x4*)&sB[(size_t)(blk+2)*512 + l*8] = v2;
            *(i32x4*)&sB[(size_t)(blk+3)*512 + l*8] = v3;
        }
        __syncthreads();

        // ---- recurrent part: K = 1024, B-frags from LDS, A pinned in VGPRs
        #pragma unroll
        for (int kk = 0; kk < KKH; ++kk){
            short8 b = *(const short8*)&sB[(size_t)(kk*64 + l)*8];
            acc = __builtin_amdgcn_mfma_f32_16x16x32_bf16(
                      __builtin_bit_cast(short8, wa[kk]), b, acc, 0, 0, 0);
        }

        float h0 = fast_tanh(acc[0]);
        float h1 = fast_tanh(acc[1]);
        float h2 = fast_tanh(acc[2]);
        float h3 = fast_tanh(acc[3]);

        if (t < SEQ-1){
            us4 hw = { f2bf(h0), f2bf(h1), f2bf(h2), f2bf(h3) };
            sys_st64(&g_h[rb ^ 1][gbg][sboff],
                     __builtin_bit_cast(unsigned long long, hw));
            hw_prev = hw;

            // ---- x-part for t+1 overlaps the h-store's LLC ack
            accX = bias;
            const float* xp = xlane + (size_t)(t+1)*IDIM;
            #pragma unroll
            for (int xk = 0; xk < KKX; ++xk){
                f32x4 v0 = *(const f32x4*)(xp + xk*32);
                f32x4 v1 = *(const f32x4*)(xp + xk*32 + 4);
                short8 bx;
                bx[0]=(short)f2bf(v0[0]); bx[1]=(short)f2bf(v0[1]);
                bx[2]=(short)f2bf(v0[2]); bx[3]=(short)f2bf(v0[3]);
                bx[4]=(short)f2bf(v1[0]); bx[5]=(short)f2bf(v1[1]);
                bx[6]=(short)f2bf(v1[2]); bx[7]=(short)f2bf(v1[3]);
                short8 a = *(const short8*)&sX[(size_t)((w*KKX + xk)*64 + l)*8];
                accX = __builtin_amdgcn_mfma_f32_16x16x32_bf16(a, bx, accX, 0, 0, 0);
            }

            asm volatile("s_waitcnt vmcnt(0)" ::: "memory");
            __syncthreads();                   // all 8 waves' h ack'd at LLC
            if (tid == 0) sys_st32(&g_flag[gbg][gr], t + 2);
        } else {
            f32x4 hf = {h0, h1, h2, h3};
            *(f32x4*)&g_hfinal[b0 + (l & 15)][r0 + rloc] = hf;
        }
    }

    // ---- epilogue: race-free flag reset for graph replay
    __syncthreads();
    if (tid == 0){
        __hip_atomic_fetch_add(&g_done[gbg*16], 1u, __ATOMIC_ACQ_REL, __HIP_MEMORY_SCOPE_SYSTEM);
        if (gr == 0){
            int guard = 0;
            while (__hip_atomic_load(&g_done[gbg*16], __ATOMIC_ACQUIRE, __HIP_MEMORY_SCOPE_SYSTEM) < GR
                   && ++guard < (1 << 22)) { }
            for (int i = 0; i < GR; ++i)
                sys_st32(&g_flag[gbg][i], 0);
            __hip_atomic_store(&g_done[gbg*16], 0u, __ATOMIC_RELAXED, __HIP_MEMORY_SCOPE_SYSTEM);
        }
    }
}

// p = w_ph @ h_final + b_p ; out[b][c]
__global__ __launch_bounds__(256, 1) void proj_kernel(
    const float* __restrict__ w_ph, const float* __restrict__ b_p, float* __restrict__ out)
{
    const int b   = blockIdx.x;
    const int tid = threadIdx.x;
    const int l   = tid & 63;
    const int wv  = tid >> 6;
    __shared__ float red[4];
    f32x4 hv = *(const f32x4*)(&g_hfinal[b][0] + tid*4);
    for (int c = 0; c < NCLS; ++c){
        f32x4 wvv = *(const f32x4*)(w_ph + c*HD + tid*4);
        float s = hv[0]*wvv[0] + hv[1]*wvv[1] + hv[2]*wvv[2] + hv[3]*wvv[3];
        #pragma unroll
        for (int off = 32; off; off >>= 1) s += __shfl_down(s, off, 64);
        if (l == 0) red[wv] = s;
        __syncthreads();
        if (tid == 0) out[b*NCLS + c] = red[0] + red[1] + red[2] + red[3] + b_p[c];
        __syncthreads();
    }
}

extern "C" void kernel_launch(void* const* d_in, const int* in_sizes, int n_in,
                              void* d_out, int out_size, void* d_ws, size_t ws_size,
                              hipStream_t stream) {
    const float* x    = (const float*)d_in[0];
    const float* w_hx = (const float*)d_in[1];
    const float* w_hh = (const float*)d_in[2];
    const float* b_h  = (const float*)d_in[3];
    const float* w_ph = (const float*)d_in[4];
    const float* b_p  = (const float*)d_in[5];

    void* args[] = { (void*)&x, (void*)&w_hx, (void*)&w_hh, (void*)&b_h };
    hipError_t err = hipLaunchCooperativeKernel((void*)rnn_main, dim3(NWG), dim3(TPB),
                                                args, 0, stream);
    if (err != hipSuccess) {
        rnn_main<<<dim3(NWG), dim3(TPB), 0, stream>>>(x, w_hx, w_hh, b_h);
    }
    proj_kernel<<<dim3(BT), dim3(256), 0, stream>>>(w_ph, b_p, (float*)d_out);
}